// Round 10
// baseline (398.795 us; speedup 1.0000x reference)
//
#include <hip/hip_runtime.h>
#include <hip/hip_bf16.h>
#include <stdint.h>

// Problem: B=1, S=4096, HIDDEN=2048, HEADS=16, HEAD_DIM=128, causal MHA.
// All inputs fp32; output fp32. Compute in bf16 MFMA with fp32 accum.
//
// Workspace layout (bytes), total ~112 MB:
//   xb    [4096][2048] bf16 @ 0         (16 MB)
//   WTall [4][2048][2048] bf16 @ 16 MB  (32 MB: WqT,WkT,WvT,WoT transposed [out][in])
//   Qb    [4096][2048] bf16 @ 48 MB
//   Kb    [4096][2048] bf16 @ 64 MB
//   VTb   [2048][4096] bf16 @ 80 MB     (V transposed per-head: row h*128+d, col s)
//   Ctx   [4096][2048] bf16 @ 96 MB

#define SQ 4096
#define HID 2048
#define NH 16
#define HD 128

typedef __attribute__((ext_vector_type(8))) short bf16x8;
typedef __attribute__((ext_vector_type(4))) float f32x4;
typedef __attribute__((ext_vector_type(16))) float f32x16;
typedef __attribute__((ext_vector_type(4))) unsigned short us4;

__device__ inline unsigned short f2bf(float f) {
    unsigned int u = __builtin_bit_cast(unsigned int, f);
    u = (u + 0x7FFFu + ((u >> 16) & 1u)) >> 16;
    return (unsigned short)u;
}

__device__ inline void gl2lds16(const void* g, void* l) {
    __builtin_amdgcn_global_load_lds(
        (const __attribute__((address_space(1))) unsigned int*)g,
        (__attribute__((address_space(3))) unsigned int*)l, 16, 0, 0);
}

// ---------------- fp32 -> bf16 convert (grid-stride, float4) ----------------
__global__ void cvt_f32_bf16(const float* __restrict__ src,
                             unsigned short* __restrict__ dst, int n) {
    int i = (blockIdx.x * blockDim.x + threadIdx.x) * 4;
    int stride = gridDim.x * blockDim.x * 4;
    for (; i < n; i += stride) {
        float4 v = *(const float4*)(src + i);
        us4 o;
        o.x = f2bf(v.x); o.y = f2bf(v.y); o.z = f2bf(v.z); o.w = f2bf(v.w);
        *(us4*)(dst + i) = o;
    }
}

// ---- transpose + convert all 4 weights: W [K][N] f32 -> WT [N][K] bf16 -----
__global__ void transcvt4(const float* __restrict__ W0, const float* __restrict__ W1,
                          const float* __restrict__ W2, const float* __restrict__ W3,
                          unsigned short* __restrict__ WTall) {
    __shared__ float tile[64][65];
    const float* W = (blockIdx.z == 0) ? W0 : (blockIdx.z == 1) ? W1
                   : (blockIdx.z == 2) ? W2 : W3;
    unsigned short* WT = WTall + (size_t)blockIdx.z * HID * HID;
    int n0 = blockIdx.x * 64, k0 = blockIdx.y * 64;
    int t = threadIdx.x;
    for (int i = 0; i < 4; i++) {
        int idx = i * 256 + t;          // 0..1023
        int k = idx >> 4;               // 64 rows, 16 float4 per row
        int n4 = (idx & 15) << 2;
        float4 v = *(const float4*)(W + (size_t)(k0 + k) * HID + n0 + n4);
        tile[k][n4 + 0] = v.x; tile[k][n4 + 1] = v.y;
        tile[k][n4 + 2] = v.z; tile[k][n4 + 3] = v.w;
    }
    __syncthreads();
    for (int i = 0; i < 4; i++) {
        int idx = i * 256 + t;
        int n = idx >> 4;
        int k4 = (idx & 15) << 2;
        us4 o;
        o.x = f2bf(tile[k4 + 0][n]); o.y = f2bf(tile[k4 + 1][n]);
        o.z = f2bf(tile[k4 + 2][n]); o.w = f2bf(tile[k4 + 3][n]);
        *(us4*)(WT + (size_t)(n0 + n) * HID + k0 + k4) = o;
    }
}

// ---------------- pipelined bf16 GEMM (2 blocks/CU for TLP overlap) ---------
// BM=BN=128, BK=64, 256 thr = 4 waves (2m x 2n), wave tile 64x64.
// 2 LDS buffers (64 KB) -> 2 blocks/CU. Issue-early/wait-late staging.
// Zero-conflict LDS slot^(row&7) swizzle (both sides). setprio on MFMA.
// OUTKIND 0: fused QKV (proj = by>>4; Q/K bf16 [M][N]+bias, V bf16 [N][M]+bias)
// OUTKIND 1: f32 out [M][N], no bias (proj=3 -> Wo).
template <int OUTKIND>
__global__ __launch_bounds__(256) void gemm_pipe(
    const unsigned short* __restrict__ A, const unsigned short* __restrict__ WTall,
    const float* __restrict__ bq, const float* __restrict__ bk,
    const float* __restrict__ bv, unsigned short* __restrict__ Qb,
    unsigned short* __restrict__ Kb, unsigned short* __restrict__ VTb,
    float* __restrict__ Cf) {
    const int K = 2048, NT = 32, M = 4096, N = 2048;
    __shared__ __align__(16) unsigned short AL[2][128 * 64];
    __shared__ __align__(16) unsigned short BL[2][128 * 64];
    int m0 = blockIdx.x * 128;
    int proj = (OUTKIND == 0) ? ((int)blockIdx.y >> 4) : 3;
    int n0 = (OUTKIND == 0) ? ((int)blockIdx.y & 15) * 128 : (int)blockIdx.y * 128;
    const unsigned short* BT = WTall + (size_t)proj * HID * HID;
    int t = threadIdx.x, lane = t & 63, w = t >> 6;
    int lr = lane & 15, hi = lane >> 4;
    int wm = w >> 1, wn = w & 1;

    auto stage = [&](int buf, int k0) {
#pragma unroll
        for (int i = 0; i < 4; i++) {
            int idx = i * 256 + t, r = idx >> 3, s = idx & 7;
            gl2lds16(A + (size_t)(m0 + r) * K + k0 + ((s ^ (r & 7)) << 3),
                     (void*)(&AL[buf][(i * 256 + w * 64) << 3]));
        }
#pragma unroll
        for (int i = 0; i < 4; i++) {
            int idx = i * 256 + t, r = idx >> 3, s = idx & 7;
            gl2lds16(BT + (size_t)(n0 + r) * K + k0 + ((s ^ (r & 7)) << 3),
                     (void*)(&BL[buf][(i * 256 + w * 64) << 3]));
        }
    };

    f32x4 acc[4][4] = {};
    stage(0, 0);

    for (int tt = 0; tt < NT; ++tt) {
        int c = tt & 1;
        asm volatile("s_waitcnt vmcnt(0)" ::: "memory");  // tile tt landed
        __builtin_amdgcn_s_barrier();
        __builtin_amdgcn_sched_barrier(0);
        if (tt + 1 < NT) stage(c ^ 1, (tt + 1) * 64);     // issue early
        const unsigned short* Al = &AL[c][0];
        const unsigned short* Bl = &BL[c][0];
#pragma unroll
        for (int kk = 0; kk < 2; ++kk) {
            int sl = ((kk * 4 + hi) ^ (lr & 7)) << 3;
            bf16x8 af[4], bfg[4];
#pragma unroll
            for (int mf = 0; mf < 4; ++mf)
                af[mf] = *(const bf16x8*)(Al + (wm * 64 + mf * 16 + lr) * 64 + sl);
#pragma unroll
            for (int nf = 0; nf < 4; ++nf)
                bfg[nf] = *(const bf16x8*)(Bl + (wn * 64 + nf * 16 + lr) * 64 + sl);
            __builtin_amdgcn_s_setprio(1);
#pragma unroll
            for (int mf = 0; mf < 4; ++mf)
#pragma unroll
                for (int nf = 0; nf < 4; ++nf)
                    acc[mf][nf] = __builtin_amdgcn_mfma_f32_16x16x32_bf16(
                        af[mf], bfg[nf], acc[mf][nf], 0, 0, 0);
            __builtin_amdgcn_s_setprio(0);
        }
    }

    int rbase = hi << 2;
    if (OUTKIND == 0) {
        const float* bias = (proj == 0) ? bq : (proj == 1) ? bk : bv;
        for (int mf = 0; mf < 4; mf++) {
            for (int nf = 0; nf < 4; nf++) {
                int n_g = n0 + wn * 64 + nf * 16 + lr;
                int m_base = m0 + wm * 64 + mf * 16 + rbase;
                float b = bias[n_g];
                if (proj < 2) {
                    unsigned short* Cb = proj ? Kb : Qb;
                    for (int r = 0; r < 4; r++)
                        Cb[(size_t)(m_base + r) * N + n_g] = f2bf(acc[mf][nf][r] + b);
                } else {
                    us4 o;
                    o.x = f2bf(acc[mf][nf][0] + b); o.y = f2bf(acc[mf][nf][1] + b);
                    o.z = f2bf(acc[mf][nf][2] + b); o.w = f2bf(acc[mf][nf][3] + b);
                    *(us4*)(VTb + (size_t)n_g * M + m_base) = o;
                }
            }
        }
    } else {
        for (int mf = 0; mf < 4; mf++)
            for (int nf = 0; nf < 4; nf++) {
                int n_g = n0 + wn * 64 + nf * 16 + lr;
                int m_base = m0 + wm * 64 + mf * 16 + rbase;
                for (int r = 0; r < 4; r++)
                    Cf[(size_t)(m_base + r) * N + n_g] = acc[mf][nf][r];
            }
    }
}

// ---------------- causal flash attention (v8: 32x32 MFMA) --------------------
// grid (NH, 32); 256 thr = 4 waves; each wave owns 32 q rows (QBLK=128).
// strip = (y<16) ? 31-y : y-16  (heavy half dispatched first; blocks i and
// i+256 land on the same CU by the round-robin heuristic and carry the SAME
// strip for paired heads -> ~68 tiles/CU uniform; speed-only assumption).
// KVBLK=64; LDS 64 KB (dbuf K[64x128] 16KB + VT[128x64] 16KB) -> 2 blocks/CU.
// 32x32x16 MFMA: 4x FLOPs per LDS byte vs 16x16x32 (LDS-read BW was the
// bottleneck pipe). Layouts (m74/m101-verified C; A/B by the k=(l>>5)*8+j
// rule): QK^T: S^T[k][q] = mfma(A=K-rows, B=Q); lane owns q=lane&31, 16 regs
// per 32-k tile, k = kt*32 + (reg&3)+8*(reg>>2)+4*(lane>>5). Softmax: 31
// in-lane ops + ONE shfl_xor(32). P packed via cvt_pk (pairs = consecutive
// k-rows); PV B-frag[kc] = wpk[kc>>1][4*(kc&1)+2*hi5 + {0,1}] from lanes q
// and q+32 (8 shfl + 4 selects, static indexing). O^T[d][q] = mfma(V^T, P^T).
// T13 defer-max; per-wave LDS-scratch transpose epilogue.
__global__ __launch_bounds__(256, 2) void attn(
    const unsigned short* __restrict__ Q, const unsigned short* __restrict__ Kc,
    const unsigned short* __restrict__ VT, unsigned short* __restrict__ O) {
    __shared__ __align__(16) unsigned short SMEM[32768];   // 64 KB
    unsigned short* KB = SMEM;              // [2][64*128]  (16 KB each)
    unsigned short* VB = SMEM + 16384;      // [2][128*64]  (16 KB each)
    int h = blockIdx.x;
    int y = blockIdx.y;
    int strip = (y < 16) ? (31 - y) : (y - 16);
    int t = threadIdx.x, lane = t & 63, w = t >> 6;
    int q5 = lane & 31, hi5 = lane >> 5;
    const float scale = 0.08838834764831845f;  // 1/sqrt(128)

    // stage K/V tile kv0 into buffer `buf`: linear LDS dest (gl2lds rule),
    // inverse-swizzled global source slot^(row&7).
    auto stage = [&](int buf, int kv0) {
#pragma unroll
        for (int i = 0; i < 4; i++) {
            int idx = i * 256 + t;            // 0..1023
            int r = idx >> 4, s = idx & 15;   // K: 64 rows x 16 slots
            gl2lds16(Kc + (size_t)(kv0 + r) * HID + h * HD + ((s ^ (r & 7)) << 3),
                     (void*)(KB + buf * 8192 + ((i * 256 + w * 64) << 3)));
            int r2 = idx >> 3, s2 = idx & 7;  // VT: 128 rows x 8 slots
            gl2lds16(VT + (size_t)(h * HD + r2) * SQ + kv0 + ((s2 ^ (r2 & 7)) << 3),
                     (void*)(VB + buf * 8192 + ((i * 256 + w * 64) << 3)));
        }
    };

    int qbase = strip * 128;
    int wq0 = qbase + w * 32;
    int qg = wq0 + q5;                 // this lane's q row

    stage(0, 0);
    bf16x8 qf[8];                      // Q B-operand: d = dd*16 + hi5*8 + j
#pragma unroll
    for (int dd = 0; dd < 8; dd++)
        qf[dd] = *(const bf16x8*)(Q + (size_t)qg * HID + h * HD + dd * 16 + hi5 * 8);
    f32x16 o_acc[4];                   // O^T: d = vt*32+(reg&3)+8*(reg>>2)+4*hi5
#pragma unroll
    for (int vt = 0; vt < 4; vt++)
#pragma unroll
        for (int r = 0; r < 16; r++) o_acc[vt][r] = 0.f;
    float m_r = -1e30f, l_r = 0.f;
    __syncthreads();

    int nt = 2 * strip + 2;
    int cur = 0;
    for (int tile = 0; tile < nt; tile++) {
        int kv0 = tile * 64;
        if (tile + 1 < nt) stage(cur ^ 1, kv0 + 64);   // async prefetch
        const unsigned short* Kl = KB + cur * 8192;
        const unsigned short* Vl = VB + cur * 8192;

        if (kv0 <= wq0 + 31) {   // not fully above this wave's diagonal
            // S^T = mfma(K, Q): 2 k-tiles x 8 d-chunks
            f32x16 sfr[2];
#pragma unroll
            for (int kt = 0; kt < 2; kt++) {
                f32x16 s;
#pragma unroll
                for (int r = 0; r < 16; r++) s[r] = 0.f;
#pragma unroll
                for (int dd = 0; dd < 8; dd++) {
                    bf16x8 kf = *(const bf16x8*)(Kl + (kt * 32 + q5) * 128 +
                                                 (((dd * 2 + hi5) ^ (q5 & 7)) << 3));
                    s = __builtin_amdgcn_mfma_f32_32x32x16_bf16(kf, qf[dd], s, 0, 0, 0);
                }
                sfr[kt] = s;
            }
            // scale + causal mask (k_g <= q_g)
            if (kv0 + 63 > wq0) {
#pragma unroll
                for (int kt = 0; kt < 2; kt++)
#pragma unroll
                    for (int r = 0; r < 16; r++) {
                        int kg = kv0 + kt * 32 + (r & 3) + 8 * (r >> 2) + 4 * hi5;
                        float v = sfr[kt][r] * scale;
                        sfr[kt][r] = (kg <= qg) ? v : -1e30f;
                    }
            } else {
#pragma unroll
                for (int kt = 0; kt < 2; kt++)
#pragma unroll
                    for (int r = 0; r < 16; r++) sfr[kt][r] *= scale;
            }
            // row max: 32 in-lane + one shfl_xor(32) (partner holds other 32 k)
            float mx = -1e30f;
#pragma unroll
            for (int kt = 0; kt < 2; kt++)
#pragma unroll
                for (int r = 0; r < 16; r++) mx = fmaxf(mx, sfr[kt][r]);
            mx = fmaxf(mx, __shfl_xor(mx, 32));
            // T13 defer-max
            if (__all((mx - m_r) <= 8.0f)) {
                float rs = 0.f;
#pragma unroll
                for (int kt = 0; kt < 2; kt++)
#pragma unroll
                    for (int r = 0; r < 16; r++) {
                        float p = __expf(sfr[kt][r] - m_r);
                        sfr[kt][r] = p;
                        rs += p;
                    }
                rs += __shfl_xor(rs, 32);
                l_r += rs;
            } else {
                float mn = fmaxf(m_r, mx);
                float alpha = __expf(m_r - mn);
                m_r = mn;
                float rs = 0.f;
#pragma unroll
                for (int kt = 0; kt < 2; kt++)
#pragma unroll
                    for (int r = 0; r < 16; r++) {
                        float p = __expf(sfr[kt][r] - mn);
                        sfr[kt][r] = p;
                        rs += p;
                    }
                rs += __shfl_xor(rs, 32);
                l_r = l_r * alpha + rs;
#pragma unroll
                for (int vt = 0; vt < 4; vt++)
#pragma unroll
                    for (int r = 0; r < 16; r++) o_acc[vt][r] *= alpha;
            }

            // pack P pairs: wpk[kt][r] = bf16(P[k-rows 2r,2r+1 of crow order])
            unsigned int wpk[2][8];
#pragma unroll
            for (int kt = 0; kt < 2; kt++)
#pragma unroll
                for (int r = 0; r < 8; r++) {
                    unsigned int d;
                    asm("v_cvt_pk_bf16_f32 %0, %1, %2"
                        : "=v"(d) : "v"(sfr[kt][2 * r]), "v"(sfr[kt][2 * r + 1]));
                    wpk[kt][r] = d;
                }
            // PV: O^T += V^T @ P^T, 4 k-chunks x 4 d-tiles
            int srcA = q5;             // source lane holding hi5_src=0 values
            int srcB = q5 + 32;        // hi5_src=1
            bool sel = hi5;
#pragma unroll
            for (int kc = 0; kc < 4; kc++) {
                int kt = kc >> 1;
                int r0 = (kc & 1) * 4;
                unsigned int a0 = __shfl(wpk[kt][r0], srcA);
                unsigned int a1 = __shfl(wpk[kt][r0 + 1], srcA);
                unsigned int a2 = __shfl(wpk[kt][r0], srcB);
                unsigned int a3 = __shfl(wpk[kt][r0 + 1], srcB);
                unsigned int b0 = __shfl(wpk[kt][r0 + 2], srcA);
                unsigned int b1 = __shfl(wpk[kt][r0 + 3], srcA);
                unsigned int b2 = __shfl(wpk[kt][r0 + 2], srcB);
                unsigned int b3 = __shfl(wpk[kt][r0 + 3], srcB);
                union { unsigned int u[4]; bf16x8 v; } pf;
                pf.u[0] = sel ? b0 : a0;
                pf.u[1] = sel ? b1 : a1;
                pf.u[2] = sel ? b2 : a2;
                pf.u[3] = sel ? b3 : a3;
#pragma unroll
                for (int vt = 0; vt < 4; vt++) {
                    bf16x8 vv = *(const bf16x8*)(Vl + (vt * 32 + q5) * 64 +
                                                 (((kc * 2 + hi5) ^ (q5 & 7)) << 3));
                    o_acc[vt] = __builtin_amdgcn_mfma_f32_32x32x16_bf16(
                        vv, pf.v, o_acc[vt], 0, 0, 0);
                }
            }
        }
        __syncthreads();   // drains prefetch vmcnt + syncs buffer flip
        cur ^= 1;
    }

    // epilogue: O^T -> O via per-wave bf16 LDS scratch (within-wave only).
    unsigned short* scr = SMEM + w * 4352;   // 32 q rows x 136 bf16
    float invl = 1.0f / l_r;
#pragma unroll
    for (int vt = 0; vt < 4; vt++)
#pragma unroll
        for (int g = 0; g < 4; g++) {
            us4 o;
            o.x = f2bf(o_acc[vt][4 * g + 0] * invl);
            o.y = f2bf(o_acc[vt][4 * g + 1] * invl);
            o.z = f2bf(o_acc[vt][4 * g + 2] * invl);
            o.w = f2bf(o_acc[vt][4 * g + 3] * invl);
            *(us4*)(scr + q5 * 136 + vt * 32 + 8 * g + 4 * hi5) = o;
        }
#pragma unroll
    for (int j = 0; j < 8; j++) {
        bf16x8 v = *(const bf16x8*)(scr + q5 * 136 + hi5 * 64 + j * 8);
        *(bf16x8*)(O + (size_t)qg * HID + h * HD + hi5 * 64 + j * 8) = v;
    }
}

// ---------------------------------------------------------------------------
extern "C" void kernel_launch(void* const* d_in, const int* in_sizes, int n_in,
                              void* d_out, int out_size, void* d_ws, size_t ws_size,
                              hipStream_t stream) {
    const float* x  = (const float*)d_in[0];
    const float* Wq = (const float*)d_in[1];
    const float* bq = (const float*)d_in[2];
    const float* Wk = (const float*)d_in[3];
    const float* bk = (const float*)d_in[4];
    const float* Wv = (const float*)d_in[5];
    const float* bv = (const float*)d_in[6];
    const float* Wo = (const float*)d_in[7];

    char* ws = (char*)d_ws;
    const size_t MB = 1024 * 1024;
    unsigned short* xb    = (unsigned short*)(ws + 0 * MB);
    unsigned short* WTall = (unsigned short*)(ws + 16 * MB);   // 4 x 8 MB
    unsigned short* Qb    = (unsigned short*)(ws + 48 * MB);
    unsigned short* Kbuf  = (unsigned short*)(ws + 64 * MB);
    unsigned short* VTb   = (unsigned short*)(ws + 80 * MB);
    unsigned short* Ctx   = (unsigned short*)(ws + 96 * MB);

    // 1. x -> bf16
    cvt_f32_bf16<<<8192, 256, 0, stream>>>(x, xb, SQ * HID);
    // 2. all 4 weights -> transposed bf16 (one dispatch)
    transcvt4<<<dim3(HID / 64, HID / 64, 4), 256, 0, stream>>>(Wq, Wk, Wv, Wo, WTall);
    // 3. fused QKV projections (1536 blocks, 2 blocks/CU resident)
    gemm_pipe<0><<<dim3(32, 48), 256, 0, stream>>>(xb, WTall, bq, bk, bv,
                                                   Qb, Kbuf, VTb, nullptr);
    // 4. causal attention (512 blocks, 2 blocks/CU, 32x32 MFMA)
    attn<<<dim3(NH, 32), 256, 0, stream>>>(Qb, Kbuf, VTb, Ctx);
    // 5. output projection (512 blocks, 2 blocks/CU resident)
    gemm_pipe<1><<<dim3(32, 16), 256, 0, stream>>>(Ctx, WTall, nullptr, nullptr,
                                                   nullptr, nullptr, nullptr,
                                                   nullptr, (float*)d_out);
}

// Round 11
// 338.611 us; speedup vs baseline: 1.1777x; 1.1777x over previous
//
#include <hip/hip_runtime.h>
#include <hip/hip_bf16.h>
#include <stdint.h>

// Problem: B=1, S=4096, HIDDEN=2048, HEADS=16, HEAD_DIM=128, causal MHA.
// All inputs fp32; output fp32. Compute in bf16 MFMA with fp32 accum.
//
// Workspace layout (bytes), total ~112 MB:
//   xb    [4096][2048] bf16 @ 0         (16 MB)
//   WTall [4][2048][2048] bf16 @ 16 MB  (32 MB: WqT,WkT,WvT,WoT transposed [out][in])
//   Qb    [4096][2048] bf16 @ 48 MB
//   Kb    [4096][2048] bf16 @ 64 MB
//   VTb   [2048][4096] bf16 @ 80 MB     (V transposed per-head: row h*128+d, col s)
//   Ctx   [4096][2048] bf16 @ 96 MB

#define SQ 4096
#define HID 2048
#define NH 16
#define HD 128

typedef __attribute__((ext_vector_type(8))) short bf16x8;
typedef __attribute__((ext_vector_type(4))) float f32x4;
typedef __attribute__((ext_vector_type(16))) float f32x16;
typedef __attribute__((ext_vector_type(4))) unsigned short us4;

__device__ inline unsigned short f2bf(float f) {
    unsigned int u = __builtin_bit_cast(unsigned int, f);
    u = (u + 0x7FFFu + ((u >> 16) & 1u)) >> 16;
    return (unsigned short)u;
}

__device__ inline void gl2lds16(const void* g, void* l) {
    __builtin_amdgcn_global_load_lds(
        (const __attribute__((address_space(1))) unsigned int*)g,
        (__attribute__((address_space(3))) unsigned int*)l, 16, 0, 0);
}

// ---------------- fp32 -> bf16 convert (grid-stride, float4) ----------------
__global__ void cvt_f32_bf16(const float* __restrict__ src,
                             unsigned short* __restrict__ dst, int n) {
    int i = (blockIdx.x * blockDim.x + threadIdx.x) * 4;
    int stride = gridDim.x * blockDim.x * 4;
    for (; i < n; i += stride) {
        float4 v = *(const float4*)(src + i);
        us4 o;
        o.x = f2bf(v.x); o.y = f2bf(v.y); o.z = f2bf(v.z); o.w = f2bf(v.w);
        *(us4*)(dst + i) = o;
    }
}

// ---- transpose + convert all 4 weights: W [K][N] f32 -> WT [N][K] bf16 -----
__global__ void transcvt4(const float* __restrict__ W0, const float* __restrict__ W1,
                          const float* __restrict__ W2, const float* __restrict__ W3,
                          unsigned short* __restrict__ WTall) {
    __shared__ float tile[64][65];
    const float* W = (blockIdx.z == 0) ? W0 : (blockIdx.z == 1) ? W1
                   : (blockIdx.z == 2) ? W2 : W3;
    unsigned short* WT = WTall + (size_t)blockIdx.z * HID * HID;
    int n0 = blockIdx.x * 64, k0 = blockIdx.y * 64;
    int t = threadIdx.x;
    for (int i = 0; i < 4; i++) {
        int idx = i * 256 + t;          // 0..1023
        int k = idx >> 4;               // 64 rows, 16 float4 per row
        int n4 = (idx & 15) << 2;
        float4 v = *(const float4*)(W + (size_t)(k0 + k) * HID + n0 + n4);
        tile[k][n4 + 0] = v.x; tile[k][n4 + 1] = v.y;
        tile[k][n4 + 2] = v.z; tile[k][n4 + 3] = v.w;
    }
    __syncthreads();
    for (int i = 0; i < 4; i++) {
        int idx = i * 256 + t;
        int n = idx >> 4;
        int k4 = (idx & 15) << 2;
        us4 o;
        o.x = f2bf(tile[k4 + 0][n]); o.y = f2bf(tile[k4 + 1][n]);
        o.z = f2bf(tile[k4 + 2][n]); o.w = f2bf(tile[k4 + 3][n]);
        *(us4*)(WT + (size_t)(n0 + n) * HID + k0 + k4) = o;
    }
}

// ---------------- pipelined bf16 GEMM (2 blocks/CU for TLP overlap) ---------
// BM=BN=128, BK=64, 256 thr = 4 waves (2m x 2n), wave tile 64x64.
// 2 LDS buffers (64 KB) -> 2 blocks/CU. Issue-early/wait-late staging.
// Zero-conflict LDS slot^(row&7) swizzle (both sides). setprio on MFMA.
// OUTKIND 0: fused QKV (proj = by>>4; Q/K bf16 [M][N]+bias, V bf16 [N][M]+bias)
// OUTKIND 1: f32 out [M][N], no bias (proj=3 -> Wo).
template <int OUTKIND>
__global__ __launch_bounds__(256) void gemm_pipe(
    const unsigned short* __restrict__ A, const unsigned short* __restrict__ WTall,
    const float* __restrict__ bq, const float* __restrict__ bk,
    const float* __restrict__ bv, unsigned short* __restrict__ Qb,
    unsigned short* __restrict__ Kb, unsigned short* __restrict__ VTb,
    float* __restrict__ Cf) {
    const int K = 2048, NT = 32, M = 4096, N = 2048;
    __shared__ __align__(16) unsigned short AL[2][128 * 64];
    __shared__ __align__(16) unsigned short BL[2][128 * 64];
    int m0 = blockIdx.x * 128;
    int proj = (OUTKIND == 0) ? ((int)blockIdx.y >> 4) : 3;
    int n0 = (OUTKIND == 0) ? ((int)blockIdx.y & 15) * 128 : (int)blockIdx.y * 128;
    const unsigned short* BT = WTall + (size_t)proj * HID * HID;
    int t = threadIdx.x, lane = t & 63, w = t >> 6;
    int lr = lane & 15, hi = lane >> 4;
    int wm = w >> 1, wn = w & 1;

    auto stage = [&](int buf, int k0) {
#pragma unroll
        for (int i = 0; i < 4; i++) {
            int idx = i * 256 + t, r = idx >> 3, s = idx & 7;
            gl2lds16(A + (size_t)(m0 + r) * K + k0 + ((s ^ (r & 7)) << 3),
                     (void*)(&AL[buf][(i * 256 + w * 64) << 3]));
        }
#pragma unroll
        for (int i = 0; i < 4; i++) {
            int idx = i * 256 + t, r = idx >> 3, s = idx & 7;
            gl2lds16(BT + (size_t)(n0 + r) * K + k0 + ((s ^ (r & 7)) << 3),
                     (void*)(&BL[buf][(i * 256 + w * 64) << 3]));
        }
    };

    f32x4 acc[4][4] = {};
    stage(0, 0);

    for (int tt = 0; tt < NT; ++tt) {
        int c = tt & 1;
        asm volatile("s_waitcnt vmcnt(0)" ::: "memory");  // tile tt landed
        __builtin_amdgcn_s_barrier();
        __builtin_amdgcn_sched_barrier(0);
        if (tt + 1 < NT) stage(c ^ 1, (tt + 1) * 64);     // issue early
        const unsigned short* Al = &AL[c][0];
        const unsigned short* Bl = &BL[c][0];
#pragma unroll
        for (int kk = 0; kk < 2; ++kk) {
            int sl = ((kk * 4 + hi) ^ (lr & 7)) << 3;
            bf16x8 af[4], bfg[4];
#pragma unroll
            for (int mf = 0; mf < 4; ++mf)
                af[mf] = *(const bf16x8*)(Al + (wm * 64 + mf * 16 + lr) * 64 + sl);
#pragma unroll
            for (int nf = 0; nf < 4; ++nf)
                bfg[nf] = *(const bf16x8*)(Bl + (wn * 64 + nf * 16 + lr) * 64 + sl);
            __builtin_amdgcn_s_setprio(1);
#pragma unroll
            for (int mf = 0; mf < 4; ++mf)
#pragma unroll
                for (int nf = 0; nf < 4; ++nf)
                    acc[mf][nf] = __builtin_amdgcn_mfma_f32_16x16x32_bf16(
                        af[mf], bfg[nf], acc[mf][nf], 0, 0, 0);
            __builtin_amdgcn_s_setprio(0);
        }
    }

    int rbase = hi << 2;
    if (OUTKIND == 0) {
        const float* bias = (proj == 0) ? bq : (proj == 1) ? bk : bv;
        for (int mf = 0; mf < 4; mf++) {
            for (int nf = 0; nf < 4; nf++) {
                int n_g = n0 + wn * 64 + nf * 16 + lr;
                int m_base = m0 + wm * 64 + mf * 16 + rbase;
                float b = bias[n_g];
                if (proj < 2) {
                    unsigned short* Cb = proj ? Kb : Qb;
                    for (int r = 0; r < 4; r++)
                        Cb[(size_t)(m_base + r) * N + n_g] = f2bf(acc[mf][nf][r] + b);
                } else {
                    us4 o;
                    o.x = f2bf(acc[mf][nf][0] + b); o.y = f2bf(acc[mf][nf][1] + b);
                    o.z = f2bf(acc[mf][nf][2] + b); o.w = f2bf(acc[mf][nf][3] + b);
                    *(us4*)(VTb + (size_t)n_g * M + m_base) = o;
                }
            }
        }
    } else {
        for (int mf = 0; mf < 4; mf++)
            for (int nf = 0; nf < 4; nf++) {
                int n_g = n0 + wn * 64 + nf * 16 + lr;
                int m_base = m0 + wm * 64 + mf * 16 + rbase;
                for (int r = 0; r < 4; r++)
                    Cf[(size_t)(m_base + r) * N + n_g] = acc[mf][nf][r];
            }
    }
}

// ---------------- causal flash attention (v9: 32x32 MFMA, split-KV groups) ---
// grid (NH, 16); 512 thr = 8 waves. Block (h, by) processes strips {31-by, by}
// SEQUENTIALLY -> every block = exactly 34+34 iterations: 256 identical
// blocks, 1/CU, zero tail (fixes v8's concurrent-imbalance collapse).
// Waves split into 2 KV-parity groups: g = w>>2 (g0 = even 64-kv tiles,
// g1 = odd), each group's 4 waves own 32 q rows each (QBLK=128). Independent
// online softmax per group; per-strip flash-combine merge through LDS.
// 4 LDS tile slots (2 groups x dbuf) = 128 KB; merge/scratch reuse post-loop.
// Per-tile math = v8's verified 32x32 path (S^T=mfma(K,Q), in-lane softmax +
// one shfl_xor(32), cvt_pk P-pack, shfl re-fragment, O^T=mfma(V^T,P^T)).
__global__ __launch_bounds__(512, 2) void attn(
    const unsigned short* __restrict__ Q, const unsigned short* __restrict__ Kc,
    const unsigned short* __restrict__ VT, unsigned short* __restrict__ O) {
    __shared__ __align__(16) unsigned short SMEM[65536];   // 128 KB
    int h = blockIdx.x;
    int by = blockIdx.y;
    int t = threadIdx.x, lane = t & 63, w = t >> 6;
    int g = w >> 2;          // KV-parity group
    int qw = w & 3;          // q sub-group (32 rows)
    int q5 = lane & 31, hi5 = lane >> 5;
    int tg = t & 255;        // thread index within group
    const float scale = 0.08838834764831845f;  // 1/sqrt(128)

    // group-local stage: 256 threads of group g stage 64-kv tile kv0 into
    // slot (g,p). Linear LDS dest, inverse-swizzled global src slot^(row&7).
    auto stageg = [&](int p, int kv0) {
        unsigned short* base = SMEM + (g * 2 + p) * 16384;
#pragma unroll
        for (int i = 0; i < 4; i++) {
            int idx = i * 256 + tg;
            int r = idx >> 4, s = idx & 15;   // K: 64 rows x 16 slots
            gl2lds16(Kc + (size_t)(kv0 + r) * HID + h * HD + ((s ^ (r & 7)) << 3),
                     (void*)(base + ((i * 256 + qw * 64) << 3)));
            int r2 = idx >> 3, s2 = idx & 7;  // VT: 128 rows x 8 slots
            gl2lds16(VT + (size_t)(h * HD + r2) * SQ + kv0 + ((s2 ^ (r2 & 7)) << 3),
                     (void*)(base + 8192 + ((i * 256 + qw * 64) << 3)));
        }
    };

    for (int sp = 0; sp < 2; sp++) {
        int st = sp ? by : (31 - by);
        int wq0 = st * 128 + qw * 32;
        int qg = wq0 + q5;                 // this lane's q row

        stageg(0, g * 64);                 // group g's first tile (kv0 = 64g)
        bf16x8 qf[8];                      // Q B-operand: d = dd*16 + hi5*8 + j
#pragma unroll
        for (int dd = 0; dd < 8; dd++)
            qf[dd] = *(const bf16x8*)(Q + (size_t)qg * HID + h * HD + dd * 16 + hi5 * 8);
        f32x16 o_acc[4];
#pragma unroll
        for (int vt = 0; vt < 4; vt++)
#pragma unroll
            for (int r = 0; r < 16; r++) o_acc[vt][r] = 0.f;
        float m_r = -1e30f, l_r = 0.f;
        __syncthreads();

        int nsteps = st + 1;               // tiles per group (nt = 2st+2 total)
        for (int it = 0; it < nsteps; it++) {
            int kv0 = (2 * it + g) * 64;
            if (it < st) stageg((it + 1) & 1, (2 * (it + 1) + g) * 64);
            const unsigned short* Kl = SMEM + (g * 2 + (it & 1)) * 16384;
            const unsigned short* Vl = Kl + 8192;

            if (kv0 <= wq0 + 31) {   // not fully above this wave's diagonal
                // S^T = mfma(K, Q): 2 k-tiles x 8 d-chunks
                f32x16 sfr[2];
#pragma unroll
                for (int kt = 0; kt < 2; kt++) {
                    f32x16 s;
#pragma unroll
                    for (int r = 0; r < 16; r++) s[r] = 0.f;
#pragma unroll
                    for (int dd = 0; dd < 8; dd++) {
                        bf16x8 kf = *(const bf16x8*)(Kl + (kt * 32 + q5) * 128 +
                                                     (((dd * 2 + hi5) ^ (q5 & 7)) << 3));
                        s = __builtin_amdgcn_mfma_f32_32x32x16_bf16(kf, qf[dd], s, 0, 0, 0);
                    }
                    sfr[kt] = s;
                }
                // scale + causal mask (k_g <= q_g)
                if (kv0 + 63 > wq0) {
#pragma unroll
                    for (int kt = 0; kt < 2; kt++)
#pragma unroll
                        for (int r = 0; r < 16; r++) {
                            int kg = kv0 + kt * 32 + (r & 3) + 8 * (r >> 2) + 4 * hi5;
                            float v = sfr[kt][r] * scale;
                            sfr[kt][r] = (kg <= qg) ? v : -1e30f;
                        }
                } else {
#pragma unroll
                    for (int kt = 0; kt < 2; kt++)
#pragma unroll
                        for (int r = 0; r < 16; r++) sfr[kt][r] *= scale;
                }
                // row max: 32 in-lane + one shfl_xor(32)
                float mx = -1e30f;
#pragma unroll
                for (int kt = 0; kt < 2; kt++)
#pragma unroll
                    for (int r = 0; r < 16; r++) mx = fmaxf(mx, sfr[kt][r]);
                mx = fmaxf(mx, __shfl_xor(mx, 32));
                // T13 defer-max
                if (__all((mx - m_r) <= 8.0f)) {
                    float rs = 0.f;
#pragma unroll
                    for (int kt = 0; kt < 2; kt++)
#pragma unroll
                        for (int r = 0; r < 16; r++) {
                            float p = __expf(sfr[kt][r] - m_r);
                            sfr[kt][r] = p;
                            rs += p;
                        }
                    rs += __shfl_xor(rs, 32);
                    l_r += rs;
                } else {
                    float mn = fmaxf(m_r, mx);
                    float alpha = __expf(m_r - mn);
                    m_r = mn;
                    float rs = 0.f;
#pragma unroll
                    for (int kt = 0; kt < 2; kt++)
#pragma unroll
                        for (int r = 0; r < 16; r++) {
                            float p = __expf(sfr[kt][r] - mn);
                            sfr[kt][r] = p;
                            rs += p;
                        }
                    rs += __shfl_xor(rs, 32);
                    l_r = l_r * alpha + rs;
#pragma unroll
                    for (int vt = 0; vt < 4; vt++)
#pragma unroll
                        for (int r = 0; r < 16; r++) o_acc[vt][r] *= alpha;
                }

                // pack P pairs
                unsigned int wpk[2][8];
#pragma unroll
                for (int kt = 0; kt < 2; kt++)
#pragma unroll
                    for (int r = 0; r < 8; r++) {
                        unsigned int d;
                        asm("v_cvt_pk_bf16_f32 %0, %1, %2"
                            : "=v"(d) : "v"(sfr[kt][2 * r]), "v"(sfr[kt][2 * r + 1]));
                        wpk[kt][r] = d;
                    }
                // PV: O^T += V^T @ P^T, 4 k-chunks x 4 d-tiles
                int srcA = q5;
                int srcB = q5 + 32;
                bool sel = hi5;
#pragma unroll
                for (int kc = 0; kc < 4; kc++) {
                    int kt = kc >> 1;
                    int r0 = (kc & 1) * 4;
                    unsigned int a0 = __shfl(wpk[kt][r0], srcA);
                    unsigned int a1 = __shfl(wpk[kt][r0 + 1], srcA);
                    unsigned int a2 = __shfl(wpk[kt][r0], srcB);
                    unsigned int a3 = __shfl(wpk[kt][r0 + 1], srcB);
                    unsigned int b0 = __shfl(wpk[kt][r0 + 2], srcA);
                    unsigned int b1 = __shfl(wpk[kt][r0 + 3], srcA);
                    unsigned int b2 = __shfl(wpk[kt][r0 + 2], srcB);
                    unsigned int b3 = __shfl(wpk[kt][r0 + 3], srcB);
                    union { unsigned int u[4]; bf16x8 v; } pf;
                    pf.u[0] = sel ? b0 : a0;
                    pf.u[1] = sel ? b1 : a1;
                    pf.u[2] = sel ? b2 : a2;
                    pf.u[3] = sel ? b3 : a3;
#pragma unroll
                    for (int vt = 0; vt < 4; vt++) {
                        bf16x8 vv = *(const bf16x8*)(Vl + (vt * 32 + q5) * 64 +
                                                     (((kc * 2 + hi5) ^ (q5 & 7)) << 3));
                        o_acc[vt] = __builtin_amdgcn_mfma_f32_32x32x16_bf16(
                            vv, pf.v, o_acc[vt], 0, 0, 0);
                    }
                }
            }
            __syncthreads();   // drains prefetch vmcnt + syncs buffer flip
        }

        // ---- per-strip merge: group 1 -> LDS, group 0 combines + stores ----
        // merge region: [4 qgroups][32 q][132] f32 = 67584 B (reuses buffers).
        float* mg = (float*)SMEM;
        float* row = mg + (qw * 32 + q5) * 132;
        if (g == 1) {
#pragma unroll
            for (int vt = 0; vt < 4; vt++)
#pragma unroll
                for (int j = 0; j < 4; j++) {
                    f32x4 c;
                    c[0] = o_acc[vt][4 * j + 0]; c[1] = o_acc[vt][4 * j + 1];
                    c[2] = o_acc[vt][4 * j + 2]; c[3] = o_acc[vt][4 * j + 3];
                    *(f32x4*)(row + vt * 32 + 8 * j + 4 * hi5) = c;
                }
            if (hi5 == 0) { row[128] = m_r; row[129] = l_r; }
        }
        __syncthreads();
        if (g == 0) {
            float m1 = row[128], l1 = row[129];
            float mm = fmaxf(m_r, m1);
            float a0 = __expf(m_r - mm), a1 = __expf(m1 - mm);
            float invl = 1.0f / (l_r * a0 + l1 * a1);
            unsigned short* scr = (unsigned short*)((char*)SMEM + 67584) + qw * 4352;
#pragma unroll
            for (int vt = 0; vt < 4; vt++)
#pragma unroll
                for (int j = 0; j < 4; j++) {
                    f32x4 o1 = *(const f32x4*)(row + vt * 32 + 8 * j + 4 * hi5);
                    us4 o;
                    o.x = f2bf((o_acc[vt][4 * j + 0] * a0 + o1[0] * a1) * invl);
                    o.y = f2bf((o_acc[vt][4 * j + 1] * a0 + o1[1] * a1) * invl);
                    o.z = f2bf((o_acc[vt][4 * j + 2] * a0 + o1[2] * a1) * invl);
                    o.w = f2bf((o_acc[vt][4 * j + 3] * a0 + o1[3] * a1) * invl);
                    *(us4*)(scr + q5 * 136 + vt * 32 + 8 * j + 4 * hi5) = o;
                }
#pragma unroll
            for (int j = 0; j < 8; j++) {
                bf16x8 v = *(const bf16x8*)(scr + q5 * 136 + hi5 * 64 + j * 8);
                *(bf16x8*)(O + (size_t)qg * HID + h * HD + hi5 * 64 + j * 8) = v;
            }
        }
        __syncthreads();   // all LDS reads done before next strip re-stages
    }
}

// ---------------------------------------------------------------------------
extern "C" void kernel_launch(void* const* d_in, const int* in_sizes, int n_in,
                              void* d_out, int out_size, void* d_ws, size_t ws_size,
                              hipStream_t stream) {
    const float* x  = (const float*)d_in[0];
    const float* Wq = (const float*)d_in[1];
    const float* bq = (const float*)d_in[2];
    const float* Wk = (const float*)d_in[3];
    const float* bk = (const float*)d_in[4];
    const float* Wv = (const float*)d_in[5];
    const float* bv = (const float*)d_in[6];
    const float* Wo = (const float*)d_in[7];

    char* ws = (char*)d_ws;
    const size_t MB = 1024 * 1024;
    unsigned short* xb    = (unsigned short*)(ws + 0 * MB);
    unsigned short* WTall = (unsigned short*)(ws + 16 * MB);   // 4 x 8 MB
    unsigned short* Qb    = (unsigned short*)(ws + 48 * MB);
    unsigned short* Kbuf  = (unsigned short*)(ws + 64 * MB);
    unsigned short* VTb   = (unsigned short*)(ws + 80 * MB);
    unsigned short* Ctx   = (unsigned short*)(ws + 96 * MB);

    // 1. x -> bf16
    cvt_f32_bf16<<<8192, 256, 0, stream>>>(x, xb, SQ * HID);
    // 2. all 4 weights -> transposed bf16 (one dispatch)
    transcvt4<<<dim3(HID / 64, HID / 64, 4), 256, 0, stream>>>(Wq, Wk, Wv, Wo, WTall);
    // 3. fused QKV projections (1536 blocks, 2 blocks/CU resident)
    gemm_pipe<0><<<dim3(32, 48), 256, 0, stream>>>(xb, WTall, bq, bk, bv,
                                                   Qb, Kbuf, VTb, nullptr);
    // 4. causal attention (256 identical blocks, 1/CU, 32x32 MFMA, split-KV)
    attn<<<dim3(NH, 16), 512, 0, stream>>>(Qb, Kbuf, VTb, Ctx);
    // 5. output projection (512 blocks, 2 blocks/CU resident)
    gemm_pipe<1><<<dim3(32, 16), 256, 0, stream>>>(Ctx, WTall, nullptr, nullptr,
                                                   nullptr, nullptr, nullptr,
                                                   nullptr, (float*)d_out);
}

// Round 12
// 302.424 us; speedup vs baseline: 1.3187x; 1.1197x over previous
//
#include <hip/hip_runtime.h>
#include <hip/hip_bf16.h>
#include <stdint.h>

// Problem: B=1, S=4096, HIDDEN=2048, HEADS=16, HEAD_DIM=128, causal MHA.
// All inputs fp32; output fp32. Compute in bf16 MFMA with fp32 accum.
//
// Workspace layout (bytes), total ~112 MB:
//   xb    [4096][2048] bf16 @ 0         (16 MB)
//   WTall [4][2048][2048] bf16 @ 16 MB  (32 MB: WqT,WkT,WvT,WoT transposed [out][in])
//   Qb    [4096][2048] bf16 @ 48 MB
//   Kb    [4096][2048] bf16 @ 64 MB
//   VTb   [2048][4096] bf16 @ 80 MB     (V transposed per-head: row h*128+d, col s)
//   Ctx   [4096][2048] bf16 @ 96 MB

#define SQ 4096
#define HID 2048
#define NH 16
#define HD 128

typedef __attribute__((ext_vector_type(8))) short bf16x8;
typedef __attribute__((ext_vector_type(4))) float f32x4;
typedef __attribute__((ext_vector_type(4))) unsigned short us4;

__device__ inline unsigned short f2bf(float f) {
    unsigned int u = __builtin_bit_cast(unsigned int, f);
    u = (u + 0x7FFFu + ((u >> 16) & 1u)) >> 16;
    return (unsigned short)u;
}

__device__ inline void gl2lds16(const void* g, void* l) {
    __builtin_amdgcn_global_load_lds(
        (const __attribute__((address_space(1))) unsigned int*)g,
        (__attribute__((address_space(3))) unsigned int*)l, 16, 0, 0);
}

// ---- merged preprocessing: z<4 -> transpose+convert W_z; z=4 -> cvt x ------
__global__ void prep(const float* __restrict__ x, const float* __restrict__ W0,
                     const float* __restrict__ W1, const float* __restrict__ W2,
                     const float* __restrict__ W3, unsigned short* __restrict__ xb,
                     unsigned short* __restrict__ WTall) {
    __shared__ float tile[64][65];
    int t = threadIdx.x;
    if (blockIdx.z == 4) {
        // x -> bf16: 1024 blocks x 256 thr x 8 iters x 4 floats = 8.39M
        int bid = blockIdx.y * 32 + blockIdx.x;
        for (int it = 0; it < 8; it++) {
            int i = (bid * 256 + t + it * 262144) * 4;
            float4 v = *(const float4*)(x + i);
            us4 o;
            o.x = f2bf(v.x); o.y = f2bf(v.y); o.z = f2bf(v.z); o.w = f2bf(v.w);
            *(us4*)(xb + i) = o;
        }
        return;
    }
    const float* W = (blockIdx.z == 0) ? W0 : (blockIdx.z == 1) ? W1
                   : (blockIdx.z == 2) ? W2 : W3;
    unsigned short* WT = WTall + (size_t)blockIdx.z * HID * HID;
    int n0 = blockIdx.x * 64, k0 = blockIdx.y * 64;
    for (int i = 0; i < 4; i++) {
        int idx = i * 256 + t;          // 0..1023
        int k = idx >> 4;               // 64 rows, 16 float4 per row
        int n4 = (idx & 15) << 2;
        float4 v = *(const float4*)(W + (size_t)(k0 + k) * HID + n0 + n4);
        tile[k][n4 + 0] = v.x; tile[k][n4 + 1] = v.y;
        tile[k][n4 + 2] = v.z; tile[k][n4 + 3] = v.w;
    }
    __syncthreads();
    for (int i = 0; i < 4; i++) {
        int idx = i * 256 + t;
        int n = idx >> 4;
        int k4 = (idx & 15) << 2;
        us4 o;
        o.x = f2bf(tile[k4 + 0][n]); o.y = f2bf(tile[k4 + 1][n]);
        o.z = f2bf(tile[k4 + 2][n]); o.w = f2bf(tile[k4 + 3][n]);
        *(us4*)(WT + (size_t)(n0 + n) * HID + k0 + k4) = o;
    }
}

// ---------------- pipelined bf16 GEMM (2 blocks/CU for TLP overlap) ---------
// BM=BN=128, BK=64, 256 thr = 4 waves (2m x 2n), wave tile 64x64.
// 2 LDS buffers (64 KB) -> 2 blocks/CU. Issue-early/wait-late staging.
// Zero-conflict LDS slot^(row&7) swizzle (both sides). setprio on MFMA.
// OUTKIND 0: fused QKV (proj = by>>4; Q/K bf16 [M][N]+bias, V bf16 [N][M]+bias)
// OUTKIND 1: f32 out [M][N], no bias (proj=3 -> Wo).
template <int OUTKIND>
__global__ __launch_bounds__(256) void gemm_pipe(
    const unsigned short* __restrict__ A, const unsigned short* __restrict__ WTall,
    const float* __restrict__ bq, const float* __restrict__ bk,
    const float* __restrict__ bv, unsigned short* __restrict__ Qb,
    unsigned short* __restrict__ Kb, unsigned short* __restrict__ VTb,
    float* __restrict__ Cf) {
    const int K = 2048, NT = 32, M = 4096, N = 2048;
    __shared__ __align__(16) unsigned short AL[2][128 * 64];
    __shared__ __align__(16) unsigned short BL[2][128 * 64];
    int m0 = blockIdx.x * 128;
    int proj = (OUTKIND == 0) ? ((int)blockIdx.y >> 4) : 3;
    int n0 = (OUTKIND == 0) ? ((int)blockIdx.y & 15) * 128 : (int)blockIdx.y * 128;
    const unsigned short* BT = WTall + (size_t)proj * HID * HID;
    int t = threadIdx.x, lane = t & 63, w = t >> 6;
    int lr = lane & 15, hi = lane >> 4;
    int wm = w >> 1, wn = w & 1;

    auto stage = [&](int buf, int k0) {
#pragma unroll
        for (int i = 0; i < 4; i++) {
            int idx = i * 256 + t, r = idx >> 3, s = idx & 7;
            gl2lds16(A + (size_t)(m0 + r) * K + k0 + ((s ^ (r & 7)) << 3),
                     (void*)(&AL[buf][(i * 256 + w * 64) << 3]));
        }
#pragma unroll
        for (int i = 0; i < 4; i++) {
            int idx = i * 256 + t, r = idx >> 3, s = idx & 7;
            gl2lds16(BT + (size_t)(n0 + r) * K + k0 + ((s ^ (r & 7)) << 3),
                     (void*)(&BL[buf][(i * 256 + w * 64) << 3]));
        }
    };

    f32x4 acc[4][4] = {};
    stage(0, 0);

    for (int tt = 0; tt < NT; ++tt) {
        int c = tt & 1;
        asm volatile("s_waitcnt vmcnt(0)" ::: "memory");  // tile tt landed
        __builtin_amdgcn_s_barrier();
        __builtin_amdgcn_sched_barrier(0);
        if (tt + 1 < NT) stage(c ^ 1, (tt + 1) * 64);     // issue early
        const unsigned short* Al = &AL[c][0];
        const unsigned short* Bl = &BL[c][0];
#pragma unroll
        for (int kk = 0; kk < 2; ++kk) {
            int sl = ((kk * 4 + hi) ^ (lr & 7)) << 3;
            bf16x8 af[4], bfg[4];
#pragma unroll
            for (int mf = 0; mf < 4; ++mf)
                af[mf] = *(const bf16x8*)(Al + (wm * 64 + mf * 16 + lr) * 64 + sl);
#pragma unroll
            for (int nf = 0; nf < 4; ++nf)
                bfg[nf] = *(const bf16x8*)(Bl + (wn * 64 + nf * 16 + lr) * 64 + sl);
            __builtin_amdgcn_s_setprio(1);
#pragma unroll
            for (int mf = 0; mf < 4; ++mf)
#pragma unroll
                for (int nf = 0; nf < 4; ++nf)
                    acc[mf][nf] = __builtin_amdgcn_mfma_f32_16x16x32_bf16(
                        af[mf], bfg[nf], acc[mf][nf], 0, 0, 0);
            __builtin_amdgcn_s_setprio(0);
        }
    }

    int rbase = hi << 2;
    if (OUTKIND == 0) {
        const float* bias = (proj == 0) ? bq : (proj == 1) ? bk : bv;
        for (int mf = 0; mf < 4; mf++) {
            for (int nf = 0; nf < 4; nf++) {
                int n_g = n0 + wn * 64 + nf * 16 + lr;
                int m_base = m0 + wm * 64 + mf * 16 + rbase;
                float b = bias[n_g];
                if (proj < 2) {
                    unsigned short* Cb = proj ? Kb : Qb;
                    for (int r = 0; r < 4; r++)
                        Cb[(size_t)(m_base + r) * N + n_g] = f2bf(acc[mf][nf][r] + b);
                } else {
                    us4 o;
                    o.x = f2bf(acc[mf][nf][0] + b); o.y = f2bf(acc[mf][nf][1] + b);
                    o.z = f2bf(acc[mf][nf][2] + b); o.w = f2bf(acc[mf][nf][3] + b);
                    *(us4*)(VTb + (size_t)n_g * M + m_base) = o;
                }
            }
        }
    } else {
        for (int mf = 0; mf < 4; mf++)
            for (int nf = 0; nf < 4; nf++) {
                int n_g = n0 + wn * 64 + nf * 16 + lr;
                int m_base = m0 + wm * 64 + mf * 16 + rbase;
                for (int r = 0; r < 4; r++)
                    Cf[(size_t)(m_base + r) * N + n_g] = acc[mf][nf][r];
            }
    }
}

// ---------------- causal flash attention (v7 + setprio) ----------------------
// REVERT to the round-9-verified v7 structure (145 us): grid (NH, 16); 512 thr
// = 8 waves; QBLK=128; block (h, by) processes strips {31-by, by} sequentially
// -> exactly 33 identical KV-tile iterations per block, 256 blocks, 1/CU.
// 128 KB LDS (dbuf K[128x128] + VT[128x128]). Swapped math (S^T = mfma(K,Q)),
// in-lane softmax, in-register P (cvt_pk + shfl), T13 defer-max, LDS-scratch
// epilogue. NEW this round: s_setprio(1) around MFMA clusters (T5, m191 +4-7%
// on attn; waves between barriers have load/compute role diversity).
__global__ __launch_bounds__(512) void attn(
    const unsigned short* __restrict__ Q, const unsigned short* __restrict__ Kc,
    const unsigned short* __restrict__ VT, unsigned short* __restrict__ O) {
    __shared__ __align__(16) unsigned short SMEM[65536];   // 128 KB
    unsigned short* KB = SMEM;              // [2][128*128]
    unsigned short* VB = SMEM + 32768;      // [2][128*128]
    int h = blockIdx.x;
    int by = blockIdx.y;
    int t = threadIdx.x, lane = t & 63, w = t >> 6;
    int lr = lane & 15, hi = lane >> 4;
    const float scale = 0.08838834764831845f;  // 1/sqrt(128)

    auto stage = [&](int buf, int kv0) {
#pragma unroll
        for (int i = 0; i < 4; i++) {
            int idx = i * 512 + t;            // 0..2047
            int r = idx >> 4, s = idx & 15;   // K: 128 rows x 16 slots
            gl2lds16(Kc + (size_t)(kv0 + r) * HID + h * HD + ((s ^ (r & 7)) << 3),
                     (void*)(KB + buf * 16384 + ((i * 512 + w * 64) << 3)));
        }
#pragma unroll
        for (int i = 0; i < 4; i++) {
            int idx = i * 512 + t;
            int r = idx >> 4, s = idx & 15;   // VT: 128 rows x 16 slots
            gl2lds16(VT + (size_t)(h * HD + r) * SQ + kv0 + ((s ^ (r & 7)) << 3),
                     (void*)(VB + buf * 16384 + ((i * 512 + w * 64) << 3)));
        }
    };

    int strips[2] = {31 - by, by};
    for (int sp = 0; sp < 2; sp++) {
        int strip = strips[sp];
        int qbase = strip * 128;
        int wq0 = qbase + w * 16;
        int qg = wq0 + lr;                 // this lane's q row

        stage(0, 0);
        bf16x8 qf[4];
        for (int ks = 0; ks < 4; ks++)
            qf[ks] = *(const bf16x8*)(Q + (size_t)qg * HID + h * HD + ks * 32 + (hi << 3));
        f32x4 o_acc[8] = {};               // O^T frags: d=16c2+4hi+reg, q=lane&15
        float m_r = -1e30f, l_r = 0.f;
        __syncthreads();

        int nt = strip + 1;                // 128-wide KV tiles for this strip
        int cur = 0;
        for (int tile = 0; tile < nt; tile++) {
            int kv0 = tile * 128;
            if (tile + 1 < nt) stage(cur ^ 1, kv0 + 128);   // async prefetch
            const unsigned short* Kl = KB + cur * 16384;
            const unsigned short* Vl = VB + cur * 16384;

            if (kv0 <= wq0 + 15) {   // not fully above this wave's diagonal
                // S^T = mfma(K, Q): sfr[c][r] = S^T[k=16c+4hi+r][q=lane&15]
                f32x4 sfr[8];
#pragma unroll
                for (int c = 0; c < 8; c++) {
                    f32x4 s = {0.f, 0.f, 0.f, 0.f};
                    __builtin_amdgcn_s_setprio(1);
#pragma unroll
                    for (int ks = 0; ks < 4; ks++) {
                        bf16x8 kf = *(const bf16x8*)(Kl + (c * 16 + lr) * 128 +
                                                     (((ks * 4 + hi) ^ (lr & 7)) << 3));
                        s = __builtin_amdgcn_mfma_f32_16x16x32_bf16(kf, qf[ks], s, 0, 0, 0);
                    }
                    __builtin_amdgcn_s_setprio(0);
                    sfr[c] = s;
                }
                // scale + causal mask (k_g <= q_g)
                if (kv0 + 127 > wq0) {
#pragma unroll
                    for (int c = 0; c < 8; c++) {
                        int kgb = kv0 + c * 16 + 4 * hi;
                        for (int r = 0; r < 4; r++) {
                            float v = sfr[c][r] * scale;
                            sfr[c][r] = (kgb + r <= qg) ? v : -1e30f;
                        }
                    }
                } else {
#pragma unroll
                    for (int c = 0; c < 8; c++)
                        for (int r = 0; r < 4; r++) sfr[c][r] *= scale;
                }
                // in-lane row max (32 values) + cross-hi (2 shfl_xor)
                float mx = -1e30f;
#pragma unroll
                for (int c = 0; c < 8; c++)
                    mx = fmaxf(mx, fmaxf(fmaxf(sfr[c][0], sfr[c][1]),
                                         fmaxf(sfr[c][2], sfr[c][3])));
                mx = fmaxf(mx, __shfl_xor(mx, 16));
                mx = fmaxf(mx, __shfl_xor(mx, 32));
                // T13 defer-max
                if (__all((mx - m_r) <= 8.0f)) {
                    float rs = 0.f;
#pragma unroll
                    for (int c = 0; c < 8; c++)
                        for (int r = 0; r < 4; r++) {
                            float p = __expf(sfr[c][r] - m_r);
                            sfr[c][r] = p;
                            rs += p;
                        }
                    rs += __shfl_xor(rs, 16);
                    rs += __shfl_xor(rs, 32);
                    l_r += rs;
                } else {
                    float mn = fmaxf(m_r, mx);
                    float alpha = __expf(m_r - mn);
                    m_r = mn;
                    float rs = 0.f;
#pragma unroll
                    for (int c = 0; c < 8; c++)
                        for (int r = 0; r < 4; r++) {
                            float p = __expf(sfr[c][r] - mn);
                            sfr[c][r] = p;
                            rs += p;
                        }
                    rs += __shfl_xor(rs, 16);
                    rs += __shfl_xor(rs, 32);
                    l_r = l_r * alpha + rs;
                    for (int c2 = 0; c2 < 8; c2++)
                        for (int r = 0; r < 4; r++) o_acc[c2][r] *= alpha;
                }

                // P^T -> PV B-operand fragments, fully in-register.
                unsigned int wpk[8][2];
#pragma unroll
                for (int c = 0; c < 8; c++)
#pragma unroll
                    for (int i = 0; i < 2; i++) {
                        unsigned int d;
                        asm("v_cvt_pk_bf16_f32 %0, %1, %2"
                            : "=v"(d) : "v"(sfr[c][2 * i]), "v"(sfr[c][2 * i + 1]));
                        wpk[c][i] = d;
                    }
                int srcA = lr + ((hi & 1) << 5);
                int srcB = srcA + 16;
                bool sel = (hi & 2);
#pragma unroll
                for (int kk = 0; kk < 4; kk++) {
                    unsigned int a0 = __shfl(wpk[2 * kk][0], srcA);
                    unsigned int a1 = __shfl(wpk[2 * kk][1], srcA);
                    unsigned int a2 = __shfl(wpk[2 * kk][0], srcB);
                    unsigned int a3 = __shfl(wpk[2 * kk][1], srcB);
                    unsigned int b0 = __shfl(wpk[2 * kk + 1][0], srcA);
                    unsigned int b1 = __shfl(wpk[2 * kk + 1][1], srcA);
                    unsigned int b2 = __shfl(wpk[2 * kk + 1][0], srcB);
                    unsigned int b3 = __shfl(wpk[2 * kk + 1][1], srcB);
                    union { unsigned int u[4]; bf16x8 v; } pf;
                    pf.u[0] = sel ? b0 : a0;
                    pf.u[1] = sel ? b1 : a1;
                    pf.u[2] = sel ? b2 : a2;
                    pf.u[3] = sel ? b3 : a3;
                    // O^T += V^T @ P^T : A = V^T (rows d), B = P^T frag
                    __builtin_amdgcn_s_setprio(1);
#pragma unroll
                    for (int c2 = 0; c2 < 8; c2++) {
                        bf16x8 vv = *(const bf16x8*)(Vl + (c2 * 16 + lr) * 128 +
                                                     (((kk * 4 + hi) ^ (lr & 7)) << 3));
                        o_acc[c2] = __builtin_amdgcn_mfma_f32_16x16x32_bf16(
                            vv, pf.v, o_acc[c2], 0, 0, 0);
                    }
                    __builtin_amdgcn_s_setprio(0);
                }
            }
            __syncthreads();   // drains prefetch vmcnt + syncs buffer flip
            cur ^= 1;
        }

        // epilogue: O^T -> O via per-wave bf16 LDS scratch (within-wave only).
        unsigned short* scr = SMEM + w * 2176;   // 16 rows x 136 bf16
        float invl = 1.0f / l_r;
        for (int c2 = 0; c2 < 8; c2++) {
            us4 o;
            o.x = f2bf(o_acc[c2][0] * invl); o.y = f2bf(o_acc[c2][1] * invl);
            o.z = f2bf(o_acc[c2][2] * invl); o.w = f2bf(o_acc[c2][3] * invl);
            *(us4*)(scr + lr * 136 + c2 * 16 + hi * 4) = o;
        }
        for (int j = 0; j < 4; j++) {
            bf16x8 v = *(const bf16x8*)(scr + lr * 136 + hi * 32 + j * 8);
            *(bf16x8*)(O + (size_t)qg * HID + h * HD + hi * 32 + j * 8) = v;
        }
        __syncthreads();   // scratch reads done before next strip re-stages
    }
}

// ---------------------------------------------------------------------------
extern "C" void kernel_launch(void* const* d_in, const int* in_sizes, int n_in,
                              void* d_out, int out_size, void* d_ws, size_t ws_size,
                              hipStream_t stream) {
    const float* x  = (const float*)d_in[0];
    const float* Wq = (const float*)d_in[1];
    const float* bq = (const float*)d_in[2];
    const float* Wk = (const float*)d_in[3];
    const float* bk = (const float*)d_in[4];
    const float* Wv = (const float*)d_in[5];
    const float* bv = (const float*)d_in[6];
    const float* Wo = (const float*)d_in[7];

    char* ws = (char*)d_ws;
    const size_t MB = 1024 * 1024;
    unsigned short* xb    = (unsigned short*)(ws + 0 * MB);
    unsigned short* WTall = (unsigned short*)(ws + 16 * MB);   // 4 x 8 MB
    unsigned short* Qb    = (unsigned short*)(ws + 48 * MB);
    unsigned short* Kbuf  = (unsigned short*)(ws + 64 * MB);
    unsigned short* VTb   = (unsigned short*)(ws + 80 * MB);
    unsigned short* Ctx   = (unsigned short*)(ws + 96 * MB);

    // 1. merged preprocessing: x -> bf16 (z=4) + 4 weights -> WT bf16 (z<4)
    prep<<<dim3(32, 32, 5), 256, 0, stream>>>(x, Wq, Wk, Wv, Wo, xb, WTall);
    // 2. fused QKV projections (1536 blocks, 2 blocks/CU resident)
    gemm_pipe<0><<<dim3(32, 48), 256, 0, stream>>>(xb, WTall, bq, bk, bv,
                                                   Qb, Kbuf, VTb, nullptr);
    // 3. causal attention (256 identical blocks, 1/CU, v7 + setprio)
    attn<<<dim3(NH, 16), 512, 0, stream>>>(Qb, Kbuf, VTb, Ctx);
    // 4. output projection (512 blocks, 2 blocks/CU resident)
    gemm_pipe<1><<<dim3(32, 16), 256, 0, stream>>>(Ctx, WTall, nullptr, nullptr,
                                                   nullptr, nullptr, nullptr,
                                                   nullptr, (float*)d_out);
}